// Round 1
// baseline (4100.361 us; speedup 1.0000x reference)
//
#include <hip/hip_runtime.h>
#include <math.h>

#define N_NODES 100000
#define N_EDGES 3200000
#define N_GRAPHS 512
#define D_FEAT 128
#define F_HID 32

// ---------------- GEMM1: x[N,128] @ W[128,32] -> out[N,32] ----------------
// block 256 = 32 nodes x 8 f4-groups; W staged in LDS.
__global__ void gemm128x32(const float* __restrict__ x, const float* __restrict__ W,
                           float* __restrict__ out, int n_nodes) {
    __shared__ float Ws[128 * 32];
    for (int i = threadIdx.x; i < 128 * 32; i += 256) Ws[i] = W[i];
    __syncthreads();
    const int fg = threadIdx.x & 7;   // which float4 of the 32 output feats
    const int nl = threadIdx.x >> 3;  // node within block (0..31)
    const int node = blockIdx.x * 32 + nl;
    if (node >= n_nodes) return;
    const float4* x4 = (const float4*)(x + (size_t)node * 128);
    const float4* Ws4 = (const float4*)Ws;  // [128][8] float4
    float4 acc = make_float4(0.f, 0.f, 0.f, 0.f);
    for (int kk = 0; kk < 32; ++kk) {
        float4 xv = x4[kk];
        int k = kk * 4;
        float4 w0 = Ws4[(k + 0) * 8 + fg];
        float4 w1 = Ws4[(k + 1) * 8 + fg];
        float4 w2 = Ws4[(k + 2) * 8 + fg];
        float4 w3 = Ws4[(k + 3) * 8 + fg];
        acc.x += xv.x * w0.x + xv.y * w1.x + xv.z * w2.x + xv.w * w3.x;
        acc.y += xv.x * w0.y + xv.y * w1.y + xv.z * w2.y + xv.w * w3.y;
        acc.z += xv.x * w0.z + xv.y * w1.z + xv.z * w2.z + xv.w * w3.z;
        acc.w += xv.x * w0.w + xv.y * w1.w + xv.z * w2.w + xv.w * w3.w;
    }
    ((float4*)(out + (size_t)node * 32))[fg] = acc;
}

// ---------------- GEMM: h[N,32] @ W[32,32] -> out[N,32] ----------------
__global__ void gemm32x32(const float* __restrict__ h, const float* __restrict__ W,
                          float* __restrict__ out, int n_nodes) {
    __shared__ float Ws[32 * 32];
    for (int i = threadIdx.x; i < 32 * 32; i += 256) Ws[i] = W[i];
    __syncthreads();
    const int fg = threadIdx.x & 7;
    const int nl = threadIdx.x >> 3;
    const int node = blockIdx.x * 32 + nl;
    if (node >= n_nodes) return;
    const float4* h4 = (const float4*)(h + (size_t)node * 32);
    const float4* Ws4 = (const float4*)Ws;  // [32][8] float4
    float4 acc = make_float4(0.f, 0.f, 0.f, 0.f);
    for (int kk = 0; kk < 8; ++kk) {
        float4 hv = h4[kk];
        int k = kk * 4;
        float4 w0 = Ws4[(k + 0) * 8 + fg];
        float4 w1 = Ws4[(k + 1) * 8 + fg];
        float4 w2 = Ws4[(k + 2) * 8 + fg];
        float4 w3 = Ws4[(k + 3) * 8 + fg];
        acc.x += hv.x * w0.x + hv.y * w1.x + hv.z * w2.x + hv.w * w3.x;
        acc.y += hv.x * w0.y + hv.y * w1.y + hv.z * w2.y + hv.w * w3.y;
        acc.z += hv.x * w0.z + hv.y * w1.z + hv.z * w2.z + hv.w * w3.z;
        acc.w += hv.x * w0.w + hv.y * w1.w + hv.z * w2.w + hv.w * w3.w;
    }
    ((float4*)(out + (size_t)node * 32))[fg] = acc;
}

// ---------------- SPMM via atomics: acc[row] += w * h[col] ----------------
// 8 threads per edge (one float4 of the 32 feats each).
__global__ void spmm_atomic(const int* __restrict__ row, const int* __restrict__ col,
                            const float* __restrict__ w, const float* __restrict__ hin,
                            float* __restrict__ acc, int n_edges) {
    int t = blockIdx.x * blockDim.x + threadIdx.x;
    int e = t >> 3;
    int fg = t & 7;
    if (e >= n_edges) return;
    int r = row[e];
    int c = col[e];
    float wt = w[e];
    float4 hv = ((const float4*)hin)[(size_t)c * 8 + fg];
    float* dst = acc + (size_t)r * 32 + fg * 4;
    atomicAdd(dst + 0, wt * hv.x);
    atomicAdd(dst + 1, wt * hv.y);
    atomicAdd(dst + 2, wt * hv.z);
    atomicAdd(dst + 3, wt * hv.w);
}

// ---------------- bias + ELU ----------------
__global__ void bias_elu(const float* __restrict__ acc, const float* __restrict__ b,
                         float* __restrict__ out, int n) {
    int i = blockIdx.x * blockDim.x + threadIdx.x;
    if (i < n) {
        float v = acc[i] + b[i & 31];
        out[i] = v > 0.f ? v : (expf(v) - 1.f);
    }
}

// ---------------- segment-sum pool (atomics) ----------------
__global__ void pool_atomic(const float* __restrict__ h, const int* __restrict__ seg,
                            float* __restrict__ g, int n_nodes) {
    int t = blockIdx.x * blockDim.x + threadIdx.x;
    int node = t >> 5;
    int f = t & 31;
    if (node >= n_nodes) return;
    atomicAdd(&g[(size_t)seg[node] * 32 + f], h[(size_t)node * 32 + f]);
}

// ---------------- MLP head: one block (1 wave) per graph ----------------
__global__ void head_mlp(const float* __restrict__ g,
                         const float* __restrict__ Wd1, const float* __restrict__ bd1,
                         const float* __restrict__ Wd2, const float* __restrict__ bd2,
                         const float* __restrict__ Wd3, const float* __restrict__ bd3,
                         float* __restrict__ out) {
    __shared__ float gr[32];
    __shared__ float s1[64];
    __shared__ float s2[32];
    const int gid = blockIdx.x;
    const int t = threadIdx.x;
    if (t < 32) gr[t] = g[(size_t)gid * 32 + t];
    __syncthreads();
    float a = bd1[t];
    for (int k = 0; k < 32; ++k) a += gr[k] * Wd1[k * 64 + t];
    s1[t] = fmaxf(a, 0.f);
    __syncthreads();
    if (t < 32) {
        float a2 = bd2[t];
        for (int k = 0; k < 64; ++k) a2 += s1[k] * Wd2[k * 32 + t];
        s2[t] = fmaxf(a2, 0.f);
    }
    __syncthreads();
    if (t == 0) {
        float a3 = bd3[0];
        for (int k = 0; k < 32; ++k) a3 += s2[k] * Wd3[k];
        out[gid] = 1.f / (1.f + expf(-a3));
    }
}

extern "C" void kernel_launch(void* const* d_in, const int* in_sizes, int n_in,
                              void* d_out, int out_size, void* d_ws, size_t ws_size,
                              hipStream_t stream) {
    const float* x  = (const float*)d_in[0];
    const int*   ei = (const int*)d_in[1];     // [2, E]
    const float* ew = (const float*)d_in[2];
    const int*   seg = (const int*)d_in[3];
    const float* W1 = (const float*)d_in[4];
    const float* b1 = (const float*)d_in[5];
    const float* W2 = (const float*)d_in[6];
    const float* b2 = (const float*)d_in[7];
    const float* W3 = (const float*)d_in[8];
    const float* b3 = (const float*)d_in[9];
    const float* Wd1 = (const float*)d_in[10];
    const float* bd1 = (const float*)d_in[11];
    const float* Wd2 = (const float*)d_in[12];
    const float* bd2 = (const float*)d_in[13];
    const float* Wd3 = (const float*)d_in[14];
    const float* bd3 = (const float*)d_in[15];
    float* out = (float*)d_out;

    const int* rowp = ei;
    const int* colp = ei + N_EDGES;

    const size_t NF = (size_t)N_NODES * F_HID;
    float* B0 = (float*)d_ws;        // projection
    float* B1 = B0 + NF;             // spmm accumulator
    float* B2 = B1 + NF;             // activated h
    float* G  = B2 + NF;             // [512, 32] pooled

    const int gemm_grid = (N_NODES + 31) / 32;              // 3125
    const int spmm_grid = (int)(((size_t)N_EDGES * 8 + 255) / 256);
    const int elu_grid  = (int)((NF + 255) / 256);
    const int pool_grid = (int)((NF + 255) / 256);

    // ---- layer 1 ----
    gemm128x32<<<gemm_grid, 256, 0, stream>>>(x, W1, B0, N_NODES);
    hipMemsetAsync(B1, 0, NF * sizeof(float), stream);
    spmm_atomic<<<spmm_grid, 256, 0, stream>>>(rowp, colp, ew, B0, B1, N_EDGES);
    bias_elu<<<elu_grid, 256, 0, stream>>>(B1, b1, B2, (int)NF);

    // ---- layer 2 ----
    gemm32x32<<<gemm_grid, 256, 0, stream>>>(B2, W2, B0, N_NODES);
    hipMemsetAsync(B1, 0, NF * sizeof(float), stream);
    spmm_atomic<<<spmm_grid, 256, 0, stream>>>(rowp, colp, ew, B0, B1, N_EDGES);
    bias_elu<<<elu_grid, 256, 0, stream>>>(B1, b2, B2, (int)NF);

    // ---- layer 3 ----
    gemm32x32<<<gemm_grid, 256, 0, stream>>>(B2, W3, B0, N_NODES);
    hipMemsetAsync(B1, 0, NF * sizeof(float), stream);
    spmm_atomic<<<spmm_grid, 256, 0, stream>>>(rowp, colp, ew, B0, B1, N_EDGES);
    bias_elu<<<elu_grid, 256, 0, stream>>>(B1, b3, B2, (int)NF);

    // ---- pool + head ----
    hipMemsetAsync(G, 0, (size_t)N_GRAPHS * F_HID * sizeof(float), stream);
    pool_atomic<<<pool_grid, 256, 0, stream>>>(B2, seg, G, N_NODES);
    head_mlp<<<N_GRAPHS, 64, 0, stream>>>(G, Wd1, bd1, Wd2, bd2, Wd3, bd3, out);
}

// Round 2
// 818.930 us; speedup vs baseline: 5.0070x; 5.0070x over previous
//
#include <hip/hip_runtime.h>
#include <math.h>

#define N_NODES 100000
#define N_EDGES 3200000
#define N_GRAPHS 512
#define D_FEAT 128
#define F_HID 32
#define SCAN_BS 512   // elements per scan block

// ---------------- GEMM1: x[N,128] @ W[128,32] -> out[N,32] ----------------
__global__ void gemm128x32(const float* __restrict__ x, const float* __restrict__ W,
                           float* __restrict__ out, int n_nodes) {
    __shared__ float Ws[128 * 32];
    for (int i = threadIdx.x; i < 128 * 32; i += 256) Ws[i] = W[i];
    __syncthreads();
    const int fg = threadIdx.x & 7;
    const int nl = threadIdx.x >> 3;
    const int node = blockIdx.x * 32 + nl;
    if (node >= n_nodes) return;
    const float4* x4 = (const float4*)(x + (size_t)node * 128);
    const float4* Ws4 = (const float4*)Ws;
    float4 acc = make_float4(0.f, 0.f, 0.f, 0.f);
    for (int kk = 0; kk < 32; ++kk) {
        float4 xv = x4[kk];
        int k = kk * 4;
        float4 w0 = Ws4[(k + 0) * 8 + fg];
        float4 w1 = Ws4[(k + 1) * 8 + fg];
        float4 w2 = Ws4[(k + 2) * 8 + fg];
        float4 w3 = Ws4[(k + 3) * 8 + fg];
        acc.x += xv.x * w0.x + xv.y * w1.x + xv.z * w2.x + xv.w * w3.x;
        acc.y += xv.x * w0.y + xv.y * w1.y + xv.z * w2.y + xv.w * w3.y;
        acc.z += xv.x * w0.z + xv.y * w1.z + xv.z * w2.z + xv.w * w3.z;
        acc.w += xv.x * w0.w + xv.y * w1.w + xv.z * w2.w + xv.w * w3.w;
    }
    ((float4*)(out + (size_t)node * 32))[fg] = acc;
}

// ---------------- GEMM: h[N,32] @ W[32,32] -> out[N,32] ----------------
__global__ void gemm32x32(const float* __restrict__ h, const float* __restrict__ W,
                          float* __restrict__ out, int n_nodes) {
    __shared__ float Ws[32 * 32];
    for (int i = threadIdx.x; i < 32 * 32; i += 256) Ws[i] = W[i];
    __syncthreads();
    const int fg = threadIdx.x & 7;
    const int nl = threadIdx.x >> 3;
    const int node = blockIdx.x * 32 + nl;
    if (node >= n_nodes) return;
    const float4* h4 = (const float4*)(h + (size_t)node * 32);
    const float4* Ws4 = (const float4*)Ws;
    float4 acc = make_float4(0.f, 0.f, 0.f, 0.f);
    for (int kk = 0; kk < 8; ++kk) {
        float4 hv = h4[kk];
        int k = kk * 4;
        float4 w0 = Ws4[(k + 0) * 8 + fg];
        float4 w1 = Ws4[(k + 1) * 8 + fg];
        float4 w2 = Ws4[(k + 2) * 8 + fg];
        float4 w3 = Ws4[(k + 3) * 8 + fg];
        acc.x += hv.x * w0.x + hv.y * w1.x + hv.z * w2.x + hv.w * w3.x;
        acc.y += hv.x * w0.y + hv.y * w1.y + hv.z * w2.y + hv.w * w3.y;
        acc.z += hv.x * w0.z + hv.y * w1.z + hv.z * w2.z + hv.w * w3.z;
        acc.w += hv.x * w0.w + hv.y * w1.w + hv.z * w2.w + hv.w * w3.w;
    }
    ((float4*)(out + (size_t)node * 32))[fg] = acc;
}

// ================= CSR build =================
__global__ void hist_rows(const int* __restrict__ row, int* __restrict__ cnt, int n_edges) {
    int e = blockIdx.x * blockDim.x + threadIdx.x;
    if (e < n_edges) atomicAdd(&cnt[row[e]], 1);
}

// per-block inclusive scan of cnt -> row_ptr[1+i] (local), bsums[b] = block total
__global__ void scan_blocks(const int* __restrict__ cnt, int* __restrict__ row_ptr,
                            int* __restrict__ bsums, int n) {
    __shared__ int s[SCAN_BS];
    int t = threadIdx.x;
    int gi = blockIdx.x * SCAN_BS + t;
    s[t] = (gi < n) ? cnt[gi] : 0;
    __syncthreads();
    for (int off = 1; off < SCAN_BS; off <<= 1) {
        int add = (t >= off) ? s[t - off] : 0;
        __syncthreads();
        s[t] += add;
        __syncthreads();
    }
    if (gi < n) row_ptr[1 + gi] = s[t];
    if (t == SCAN_BS - 1) bsums[blockIdx.x] = s[t];
}

// single block: exclusive scan of bsums[nb] in place
__global__ void scan_sums(int* __restrict__ bsums, int nb) {
    __shared__ int s[256];
    int t = threadIdx.x;
    s[t] = (t < nb) ? bsums[t] : 0;
    __syncthreads();
    for (int off = 1; off < 256; off <<= 1) {
        int add = (t >= off) ? s[t - off] : 0;
        __syncthreads();
        s[t] += add;
        __syncthreads();
    }
    if (t < nb) bsums[t] = (t == 0) ? 0 : s[t - 1];
}

__global__ void scan_fixup(int* __restrict__ row_ptr, const int* __restrict__ bsums, int n) {
    int i = blockIdx.x * blockDim.x + threadIdx.x;
    if (i < n) row_ptr[1 + i] += bsums[i / SCAN_BS];
    if (i == 0) row_ptr[0] = 0;
}

__global__ void copy_cursor(const int* __restrict__ row_ptr, int* __restrict__ cursor, int n) {
    int i = blockIdx.x * blockDim.x + threadIdx.x;
    if (i < n) cursor[i] = row_ptr[i];
}

__global__ void csr_scatter(const int* __restrict__ row, const int* __restrict__ col,
                            const float* __restrict__ w, int* __restrict__ cursor,
                            int* __restrict__ cols_s, float* __restrict__ w_s, int n_edges) {
    int e = blockIdx.x * blockDim.x + threadIdx.x;
    if (e >= n_edges) return;
    int pos = atomicAdd(&cursor[row[e]], 1);
    cols_s[pos] = col[e];
    w_s[pos] = w[e];
}

// ================= SPMM (CSR gather) + bias + ELU =================
// 8 threads per node, each owns a float4 of the 32 feats. 32 nodes / 256-block.
__global__ void spmm_csr(const int* __restrict__ rp, const int* __restrict__ cols,
                         const float* __restrict__ wv, const float* __restrict__ hin,
                         const float* __restrict__ b, float* __restrict__ out, int n_nodes) {
    const int fg = threadIdx.x & 7;
    const int node = blockIdx.x * 32 + (threadIdx.x >> 3);
    if (node >= n_nodes) return;
    const int s = rp[node], e = rp[node + 1];
    const float4* h4 = (const float4*)hin;
    float4 acc = make_float4(0.f, 0.f, 0.f, 0.f);
    for (int i = s; i < e; ++i) {
        int c = cols[i];
        float wt = wv[i];
        float4 hv = h4[(size_t)c * 8 + fg];
        acc.x += wt * hv.x;
        acc.y += wt * hv.y;
        acc.z += wt * hv.z;
        acc.w += wt * hv.w;
    }
    float4 bv = ((const float4*)b)[fg];
    acc.x += bv.x; acc.y += bv.y; acc.z += bv.z; acc.w += bv.w;
    acc.x = acc.x > 0.f ? acc.x : (expf(acc.x) - 1.f);
    acc.y = acc.y > 0.f ? acc.y : (expf(acc.y) - 1.f);
    acc.z = acc.z > 0.f ? acc.z : (expf(acc.z) - 1.f);
    acc.w = acc.w > 0.f ? acc.w : (expf(acc.w) - 1.f);
    ((float4*)(out + (size_t)node * 32))[fg] = acc;
}

// ================= pool: sorted seg run-accumulation =================
__global__ void pool_seg(const float* __restrict__ h, const int* __restrict__ seg,
                         float* __restrict__ g, int n_nodes) {
    const int t = threadIdx.x;
    const int f = t & 31;
    const int sub = t >> 5;           // 0..7
    const int base = blockIdx.x * 512;
    float run = 0.f;
    int cur = -1;
    for (int i = 0; i < 64; ++i) {
        int node = base + sub + i * 8;
        if (node >= n_nodes) break;
        int sg = seg[node];
        if (sg != cur) {
            if (cur >= 0) atomicAdd(&g[(size_t)cur * 32 + f], run);
            cur = sg;
            run = 0.f;
        }
        run += h[(size_t)node * 32 + f];
    }
    if (cur >= 0) atomicAdd(&g[(size_t)cur * 32 + f], run);
}

// ================= MLP head =================
__global__ void head_mlp(const float* __restrict__ g,
                         const float* __restrict__ Wd1, const float* __restrict__ bd1,
                         const float* __restrict__ Wd2, const float* __restrict__ bd2,
                         const float* __restrict__ Wd3, const float* __restrict__ bd3,
                         float* __restrict__ out) {
    __shared__ float gr[32];
    __shared__ float s1[64];
    __shared__ float s2[32];
    const int gid = blockIdx.x;
    const int t = threadIdx.x;
    if (t < 32) gr[t] = g[(size_t)gid * 32 + t];
    __syncthreads();
    float a = bd1[t];
    for (int k = 0; k < 32; ++k) a += gr[k] * Wd1[k * 64 + t];
    s1[t] = fmaxf(a, 0.f);
    __syncthreads();
    if (t < 32) {
        float a2 = bd2[t];
        for (int k = 0; k < 64; ++k) a2 += s1[k] * Wd2[k * 32 + t];
        s2[t] = fmaxf(a2, 0.f);
    }
    __syncthreads();
    if (t == 0) {
        float a3 = bd3[0];
        for (int k = 0; k < 32; ++k) a3 += s2[k] * Wd3[k];
        out[gid] = 1.f / (1.f + expf(-a3));
    }
}

extern "C" void kernel_launch(void* const* d_in, const int* in_sizes, int n_in,
                              void* d_out, int out_size, void* d_ws, size_t ws_size,
                              hipStream_t stream) {
    const float* x   = (const float*)d_in[0];
    const int*   ei  = (const int*)d_in[1];
    const float* ew  = (const float*)d_in[2];
    const int*   seg = (const int*)d_in[3];
    const float* W1  = (const float*)d_in[4];
    const float* b1  = (const float*)d_in[5];
    const float* W2  = (const float*)d_in[6];
    const float* b2  = (const float*)d_in[7];
    const float* W3  = (const float*)d_in[8];
    const float* b3  = (const float*)d_in[9];
    const float* Wd1 = (const float*)d_in[10];
    const float* bd1 = (const float*)d_in[11];
    const float* Wd2 = (const float*)d_in[12];
    const float* bd2 = (const float*)d_in[13];
    const float* Wd3 = (const float*)d_in[14];
    const float* bd3 = (const float*)d_in[15];
    float* out = (float*)d_out;

    const int* rowp = ei;
    const int* colp = ei + N_EDGES;

    const size_t NF = (size_t)N_NODES * F_HID;
    float* B0      = (float*)d_ws;          // projected h
    float* B2      = B0 + NF;               // activated h
    float* w_s     = B2 + NF;               // sorted edge weights [E]
    int*   cols_s  = (int*)(w_s + N_EDGES); // sorted cols [E]
    int*   row_ptr = cols_s + N_EDGES;      // [N+1]
    int*   cnt     = row_ptr + N_NODES + 1; // [N] (hist, then cursor)
    int*   bsums   = cnt + N_NODES;         // [256]
    float* G       = (float*)(bsums + 256); // [512,32]

    const int nb_scan = (N_NODES + SCAN_BS - 1) / SCAN_BS;  // 196
    const int edge_grid = (N_EDGES + 255) / 256;            // 12500
    const int node_grid = (N_NODES + 255) / 256;
    const int gemm_grid = (N_NODES + 31) / 32;              // 3125
    const int pool_grid = (N_NODES + 511) / 512;            // 196

    // ---- build CSR (once per call) ----
    hipMemsetAsync(cnt, 0, N_NODES * sizeof(int), stream);
    hist_rows<<<edge_grid, 256, 0, stream>>>(rowp, cnt, N_EDGES);
    scan_blocks<<<nb_scan, SCAN_BS, 0, stream>>>(cnt, row_ptr, bsums, N_NODES);
    scan_sums<<<1, 256, 0, stream>>>(bsums, nb_scan);
    scan_fixup<<<node_grid, 256, 0, stream>>>(row_ptr, bsums, N_NODES);
    copy_cursor<<<node_grid, 256, 0, stream>>>(row_ptr, cnt, N_NODES);
    csr_scatter<<<edge_grid, 256, 0, stream>>>(rowp, colp, ew, cnt, cols_s, w_s, N_EDGES);

    // ---- layer 1 ----
    gemm128x32<<<gemm_grid, 256, 0, stream>>>(x, W1, B0, N_NODES);
    spmm_csr<<<gemm_grid, 256, 0, stream>>>(row_ptr, cols_s, w_s, B0, b1, B2, N_NODES);

    // ---- layer 2 ----
    gemm32x32<<<gemm_grid, 256, 0, stream>>>(B2, W2, B0, N_NODES);
    spmm_csr<<<gemm_grid, 256, 0, stream>>>(row_ptr, cols_s, w_s, B0, b2, B2, N_NODES);

    // ---- layer 3 ----
    gemm32x32<<<gemm_grid, 256, 0, stream>>>(B2, W3, B0, N_NODES);
    spmm_csr<<<gemm_grid, 256, 0, stream>>>(row_ptr, cols_s, w_s, B0, b3, B2, N_NODES);

    // ---- pool + head ----
    hipMemsetAsync(G, 0, (size_t)N_GRAPHS * F_HID * sizeof(float), stream);
    pool_seg<<<pool_grid, 256, 0, stream>>>(B2, seg, G, N_NODES);
    head_mlp<<<N_GRAPHS, 64, 0, stream>>>(G, Wd1, bd1, Wd2, bd2, Wd3, bd3, out);
}